// Round 13
// baseline (258.925 us; speedup 1.0000x reference)
//
#include <hip/hip_runtime.h>

#define N_NODES 50000
#define IN_CH   128
#define OUT_CH  64
#define N_EDGES 800000
#define P_PART  32     // target partitions
#define C_CHUNK 8      // edge chunks (bid&7 -> chunk = XCD affinity heuristic)
#define T_PER_P 1563   // ceil(N_NODES / P_PART)
#define E_PER_C 100000 // N_EDGES / C_CHUNK
#define CAP_C   16     // per-(chunk,target) capacity; Poisson(2), P(>16)~1e-9
#define GEMM_B  782    // ceil(50000 / 64)

// NOTE (R9): ~92us of dur_us is the harness's 256MB ws poison fills inside the
// timed region. Controllable kernel budget is dur_us - ~92us.
// NOTE (R1): harness materializes integer inputs as int32 (not int64).
// NOTE (R12): random 2B global scatter stores from all XCDs -> ~40MB partial-
// line writebacks regardless of layout; fix = partition-owned scatter (LDS
// counters, exclusive dense sub-regions, no global atomics).

// bf16 pack (RNE), two floats -> one dword (lo=a, hi=b)
__device__ __forceinline__ unsigned int bpack(float a, float b) {
    unsigned int ua = __float_as_uint(a), ub = __float_as_uint(b);
    unsigned int ra = (ua + 0x7fffu + ((ua >> 16) & 1u)) >> 16;
    unsigned int rb = (ub + 0x7fffu + ((ub >> 16) & 1u)) & 0xffff0000u;
    return (ra & 0xffffu) | rb;
}

// ======================= K1a: partition-owned edge scatter =======================
// Block (p = bid>>3, c = bid&7): stream chunk c (coalesced int4), keep targets
// in [p*T_PER_P, ...+tsz), count in LDS, write esrc planes c*16+pos (exclusive
// region -> dense L2-merged writebacks), then dump counts to fill8[c][t].

__global__ __launch_bounds__(256) void scatter_part(const int* __restrict__ row,
        const int* __restrict__ col, unsigned short* __restrict__ esrc,
        unsigned char* __restrict__ fill8) {
    __shared__ int lcnt[T_PER_P];
    const int p  = blockIdx.x >> 3;
    const int c  = blockIdx.x & 7;
    const int t0 = p * T_PER_P;
    int tsz = N_NODES - t0; if (tsz > T_PER_P) tsz = T_PER_P;
    for (int i = threadIdx.x; i < T_PER_P; i += 256) lcnt[i] = 0;
    __syncthreads();

    const int e0 = c * E_PER_C;
    for (int base = threadIdx.x * 4; base < E_PER_C; base += 256 * 4) {
        int e = e0 + base;                      // base%4==0 -> int4 aligned
        int4 t4 = *(const int4*)&col[e];
        int4 s4 = *(const int4*)&row[e];
        const int ts[4] = { t4.x, t4.y, t4.z, t4.w };
        const int ss[4] = { s4.x, s4.y, s4.z, s4.w };
        #pragma unroll
        for (int j = 0; j < 4; ++j) {
            int tl = ts[j] - t0;
            if (tl >= 0 && tl < tsz) {
                int pos = atomicAdd(&lcnt[tl], 1);   // LDS atomic
                if (pos < CAP_C)
                    esrc[(size_t)(c * CAP_C + pos) * N_NODES + ts[j]] =
                        (unsigned short)ss[j];
            }
        }
    }
    __syncthreads();
    for (int i = threadIdx.x; i < tsz; i += 256) {
        int v = lcnt[i]; if (v > CAP_C) v = CAP_C;
        fill8[(size_t)c * N_NODES + t0 + i] = (unsigned char)v;
    }
}

// ======================= K1b: gemm y = x @ W (isolated; body = R12) =======================
// 8 lanes per node (q owns channels q*8..+7 and k-slice [q*16,+16) in regs);
// thread = 2 nodes; x broadcast via width-8 shfl; W-only LDS (32KB).

__global__ __launch_bounds__(256) void gemm_x(const float* __restrict__ x,
        const float* __restrict__ W, float* __restrict__ y) {
    const int tid = threadIdx.x;
    __shared__ float sW[IN_CH * OUT_CH];   // 32 KB, [k][c]
    {
        const float4* W4 = (const float4*)W;
        float4* sW4 = (float4*)sW;
        #pragma unroll
        for (int i = 0; i < 8; ++i) sW4[tid + i * 256] = W4[tid + i * 256];
    }
    const int q   = tid & 7;
    const int seg = tid >> 3;
    const int n0  = blockIdx.x * 64;
    const int na  = n0 + seg;
    const int nb  = n0 + 32 + seg;
    const int ca  = (na < N_NODES) ? na : N_NODES - 1;
    const int cb  = (nb < N_NODES) ? nb : N_NODES - 1;

    float xa[16], xb[16];
    {
        const float4* ra = (const float4*)(x + (size_t)ca * IN_CH + q * 16);
        const float4* rb = (const float4*)(x + (size_t)cb * IN_CH + q * 16);
        #pragma unroll
        for (int j = 0; j < 4; ++j) {
            ((float4*)xa)[j] = ra[j];
            ((float4*)xb)[j] = rb[j];
        }
    }
    __syncthreads();

    float acca[8] = {}, accb[8] = {};
    for (int k0 = 0; k0 < 8; ++k0) {
        #pragma unroll
        for (int i = 0; i < 16; ++i) {
            float ka = __shfl(xa[i], k0, 8);
            float kb = __shfl(xb[i], k0, 8);
            const float* wr = &sW[((k0 * 16 + i) << 6) + q * 8];
            float4 w0 = *(const float4*)wr;
            float4 w1 = *(const float4*)(wr + 4);
            acca[0] += ka * w0.x; acca[1] += ka * w0.y;
            acca[2] += ka * w0.z; acca[3] += ka * w0.w;
            acca[4] += ka * w1.x; acca[5] += ka * w1.y;
            acca[6] += ka * w1.z; acca[7] += ka * w1.w;
            accb[0] += kb * w0.x; accb[1] += kb * w0.y;
            accb[2] += kb * w0.z; accb[3] += kb * w0.w;
            accb[4] += kb * w1.x; accb[5] += kb * w1.y;
            accb[6] += kb * w1.z; accb[7] += kb * w1.w;
        }
    }
    if (na < N_NODES) {
        *(float4*)(y + (size_t)na * OUT_CH + q * 8) =
            make_float4(acca[0], acca[1], acca[2], acca[3]);
        *(float4*)(y + (size_t)na * OUT_CH + q * 8 + 4) =
            make_float4(acca[4], acca[5], acca[6], acca[7]);
    }
    if (nb < N_NODES) {
        *(float4*)(y + (size_t)nb * OUT_CH + q * 8) =
            make_float4(accb[0], accb[1], accb[2], accb[3]);
        *(float4*)(y + (size_t)nb * OUT_CH + q * 8 + 4) =
            make_float4(accb[4], accb[5], accb[6], accb[7]);
    }
}

// ======================= K2: z0 = D^-1/2 y (fp32 -> bf16) =======================

__global__ __launch_bounds__(256) void scale_z0(const float* __restrict__ y,
        const unsigned char* __restrict__ fill8, uint4* __restrict__ z0) {
    int gid = blockIdx.x * 256 + threadIdx.x;   // (n,q)
    if (gid >= N_NODES * 8) return;
    int n = gid >> 3, q = gid & 7;
    int deg = 0;
    #pragma unroll
    for (int c = 0; c < C_CHUNK; ++c) deg += fill8[(size_t)c * N_NODES + n];
    float d = rsqrtf((float)(deg + 1));
    float4 a = ((const float4*)y)[n * 16 + q * 2];
    float4 b = ((const float4*)y)[n * 16 + q * 2 + 1];
    uint4 pk;
    pk.x = bpack(d * a.x, d * a.y);
    pk.y = bpack(d * a.z, d * a.w);
    pk.z = bpack(d * b.x, d * b.y);
    pk.w = bpack(d * b.z, d * b.w);
    z0[gid] = pk;
}

// ======================= K3/K4: unweighted (A+I) gather + diagonal epilogue =======================
// Wave per target; 8 groups x 8 lanes; lane q holds channels q*8..+7 (uint4 of
// 8 bf16). Edge lists are now per-chunk (8 lists, Poisson(2) each); all 8
// fill bytes preloaded (independent loads), then per-chunk rounds.

__global__ __launch_bounds__(256) void hop_gather(const uint4* __restrict__ hin,
        void* __restrict__ hout, const unsigned char* __restrict__ fill8,
        const unsigned short* __restrict__ esrc, const float* __restrict__ bias,
        int last) {
    int lane = threadIdx.x & 63;
    int g = lane >> 3;
    int q = lane & 7;
    int t = __builtin_amdgcn_readfirstlane(blockIdx.x * 4 + (threadIdx.x >> 6));
    if (t >= N_NODES) return;

    int dcs[C_CHUNK];
    int deg = 0;
    #pragma unroll
    for (int c = 0; c < C_CHUNK; ++c) {        // 8 independent byte loads
        dcs[c] = fill8[(size_t)c * N_NODES + t];
        deg += dcs[c];
    }

    float acc[8] = {};
    if (g == 0) {                      // self-loop row (weight 1)
        uint4 r = hin[t * 8 + q];
        const unsigned int rw[4] = { r.x, r.y, r.z, r.w };
        #pragma unroll
        for (int j = 0; j < 4; ++j) {
            acc[2 * j]     = __uint_as_float(rw[j] << 16);
            acc[2 * j + 1] = __uint_as_float(rw[j] & 0xffff0000u);
        }
    }
    #pragma unroll
    for (int c = 0; c < C_CHUNK; ++c) {
        int dc = dcs[c];
        for (int base = 0; base < dc; base += 8) {
            int e = base + g;
            if (e < dc) {
                int s = (int)esrc[(size_t)(c * CAP_C + e) * N_NODES + t];
                uint4 r = hin[s * 8 + q];              // 128B row per group
                const unsigned int rw[4] = { r.x, r.y, r.z, r.w };
                #pragma unroll
                for (int j = 0; j < 4; ++j) {
                    acc[2 * j]     += __uint_as_float(rw[j] << 16);
                    acc[2 * j + 1] += __uint_as_float(rw[j] & 0xffff0000u);
                }
            }
        }
    }
    #pragma unroll
    for (int j = 0; j < 8; ++j) {
        acc[j] += __shfl_xor(acc[j], 8);
        acc[j] += __shfl_xor(acc[j], 16);
        acc[j] += __shfl_xor(acc[j], 32);
    }
    if (g == 0) {
        if (!last) {                   // z1 = u1 / deg  (bf16)
            float rdeg = 1.0f / (float)(deg + 1);
            uint4 pk;
            pk.x = bpack(acc[0] * rdeg, acc[1] * rdeg);
            pk.y = bpack(acc[2] * rdeg, acc[3] * rdeg);
            pk.z = bpack(acc[4] * rdeg, acc[5] * rdeg);
            pk.w = bpack(acc[6] * rdeg, acc[7] * rdeg);
            ((uint4*)hout)[t * 8 + q] = pk;
        } else {                       // out = dinv*u2 + b  (fp32)
            float d = rsqrtf((float)(deg + 1));
            float4 b0 = ((const float4*)bias)[q * 2];
            float4 b1 = ((const float4*)bias)[q * 2 + 1];
            float4 o0 = make_float4(d * acc[0] + b0.x, d * acc[1] + b0.y,
                                    d * acc[2] + b0.z, d * acc[3] + b0.w);
            float4 o1 = make_float4(d * acc[4] + b1.x, d * acc[5] + b1.y,
                                    d * acc[6] + b1.z, d * acc[7] + b1.w);
            ((float4*)hout)[t * 16 + q * 2]     = o0;
            ((float4*)hout)[t * 16 + q * 2 + 1] = o1;
        }
    }
}

// ======================= launch =======================

extern "C" void kernel_launch(void* const* d_in, const int* in_sizes, int n_in,
                              void* d_out, int out_size, void* d_ws, size_t ws_size,
                              hipStream_t stream) {
    const float* x  = (const float*)d_in[0];
    const int*   ei = (const int*)d_in[1];   // edge_index [2,E], int32 on device
    const float* W  = (const float*)d_in[2];
    const float* b  = (const float*)d_in[3];
    float*       out = (float*)d_out;

    const int* row = ei;
    const int* col = ei + N_EDGES;

    // ws (~39 MB): esrc(128 planes ushort) | fill8 | y(fp32) | z0(bf16) | z1(bf16)
    char* ws = (char*)d_ws;
    size_t a = 0;
    auto alloc = [&](size_t bytes) { char* p = ws + a; a = (a + bytes + 255) & ~(size_t)255; return p; };
    unsigned short* esrc  = (unsigned short*)alloc((size_t)C_CHUNK * CAP_C * N_NODES * 2);
    unsigned char*  fill8 = (unsigned char*) alloc((size_t)C_CHUNK * N_NODES);
    float*          y     = (float*)         alloc((size_t)N_NODES * OUT_CH * sizeof(float));
    unsigned int*   z0    = (unsigned int*)  alloc((size_t)N_NODES * OUT_CH * 2);
    unsigned int*   z1    = (unsigned int*)  alloc((size_t)N_NODES * OUT_CH * 2);

    const int B = 256;
    int gS = (N_NODES * 8 + B - 1) / B;   // 1563
    int gH = (N_NODES + 3) / 4;           // 12500

    // K1a: partition-owned scatter (no global atomics, no memset needed)
    scatter_part<<<P_PART * C_CHUNK, B, 0, stream>>>(row, col, esrc, fill8);
    // K1b: gemm (isolated for attribution)
    gemm_x<<<GEMM_B, B, 0, stream>>>(x, W, y);
    // K2: z0 = D^-1/2 y
    scale_z0<<<gS, B, 0, stream>>>(y, fill8, (uint4*)z0);
    // K3: hop1: z1 = D^-1 (A+I) z0
    hop_gather<<<gH, B, 0, stream>>>((const uint4*)z0, (void*)z1, fill8, esrc, b, 0);
    // K4: hop2: out = D^-1/2 (A+I) z1 + b
    hop_gather<<<gH, B, 0, stream>>>((const uint4*)z1, (void*)out, fill8, esrc, b, 1);
}

// Round 14
// 183.545 us; speedup vs baseline: 1.4107x; 1.4107x over previous
//
#include <hip/hip_runtime.h>

#define N_NODES 50000
#define IN_CH   128
#define OUT_CH  64
#define N_EDGES 800000
#define NBINS   49      // bin = t >> 10
#define LBCAP   128     // per-(block,bin) LDS cap; Poisson(64), P(>128)~1e-13
#define BINCAP  20000   // per-bin global cap; mean 16.3K, sd 128
#define PCAP    64      // esrc planes; deg Poisson(16), P(>64)~1e-18
#define WT_STR  136     // bf16 per WT row (16B-aligned rows, bank-spread)

// NOTE (R9): ~92us of dur_us is harness 256MB ws poison fills. Budget = dur-92.
// NOTE (R1): integer inputs arrive as int32.
// NOTE (R12/13): random fine-grain global stores -> ~50MB line-granule L2->MALL
// traffic (~46us); partition-owned dense writes fix it but must not re-read the
// edge list (R13: 32x re-read at 1 block/CU = 73us). Two-phase binning does both.
// NOTE (R13): per-k shfl/LDS dependent chains make a 45us gemm out of 5us of FMA.

using short8  = __attribute__((ext_vector_type(8))) short;
using float4v = __attribute__((ext_vector_type(4))) float;

__device__ __forceinline__ unsigned int bpack(float a, float b) {
    unsigned int ua = __float_as_uint(a), ub = __float_as_uint(b);
    unsigned int ra = (ua + 0x7fffu + ((ua >> 16) & 1u)) >> 16;
    unsigned int rb = (ub + 0x7fffu + ((ub >> 16) & 1u)) & 0xffff0000u;
    return (ra & 0xffffu) | rb;
}

// =================== K1: scatter phase A — bin edges, dense append ===================
__global__ __launch_bounds__(256) void scatter_a(const int* __restrict__ row,
        const int* __restrict__ col, unsigned int* __restrict__ binbuf,
        int* __restrict__ gcur) {
    __shared__ unsigned int sbuf[NBINS][LBCAP];   // 25 KB
    __shared__ int scnt[NBINS];
    __shared__ int sdst[NBINS];
    const int tid = threadIdx.x;
    for (int i = tid; i < NBINS; i += 256) scnt[i] = 0;
    __syncthreads();
    const int e0 = blockIdx.x * (N_EDGES / 256);            // 3125 edges/block
    for (int i = tid; i < N_EDGES / 256; i += 256) {        // coalesced read-once
        int e = e0 + i;
        int s = row[e], t = col[e];
        int b = t >> 10;
        int pos = atomicAdd(&scnt[b], 1);                   // LDS atomic
        if (pos < LBCAP)
            sbuf[b][pos] = ((unsigned)(t & 1023) << 16) | (unsigned)s;
    }
    __syncthreads();
    for (int b = tid; b < NBINS; b += 256) {                // 1 global atomic/bin
        int c = scnt[b]; if (c > LBCAP) c = LBCAP; scnt[b] = c;
        sdst[b] = atomicAdd(&gcur[b], c);
    }
    __syncthreads();
    for (int b = 0; b < NBINS; ++b) {                       // dense coalesced copy
        int c = scnt[b], d = sdst[b];
        for (int i = tid; i < c; i += 256)
            binbuf[(size_t)b * BINCAP + d + i] = sbuf[b][i];
    }
}

// =================== K2: scatter phase B — per-bin CSR build (single-writer) ===================
__global__ __launch_bounds__(1024) void scatter_b(const unsigned int* __restrict__ binbuf,
        const int* __restrict__ gcur, unsigned short* __restrict__ esrc,
        unsigned char* __restrict__ fill8) {
    __shared__ int lcnt[1024];
    const int b  = blockIdx.x;
    const int t0 = b << 10;
    const int tid = threadIdx.x;
    lcnt[tid] = 0;
    __syncthreads();
    int cnt = gcur[b]; if (cnt > BINCAP) cnt = BINCAP;
    const unsigned int* src = binbuf + (size_t)b * BINCAP;
    for (int i = tid; i < cnt; i += 1024) {
        unsigned int e = src[i];                 // dense read
        int tl = e >> 16;
        int pos = atomicAdd(&lcnt[tl], 1);       // LDS atomic
        int t = t0 + tl;
        if (pos < PCAP && t < N_NODES)           // 2KB stripes, single writer
            esrc[(size_t)pos * N_NODES + t] = (unsigned short)(e & 0xffffu);
    }
    __syncthreads();
    int t = t0 + tid;
    if (t < N_NODES) {
        int v = lcnt[tid]; if (v > PCAP) v = PCAP;
        fill8[t] = (unsigned char)v;
    }
}

// =================== K3: MFMA gemm y = x @ W (bf16 in, fp32 out) ===================
// Wave = 16-node tile x 64 ch, K=128. A[m=lane&15][k=quad*8+j] read from global
// fp32 + packed to bf16 in-reg; B-frags (WT bf16 in LDS, transposed) loaded once
// and held in VGPRs; C/D: col=lane&15, row=quad*4+reg. No per-k LDS ops.
__global__ __launch_bounds__(256) void gemm_mfma(const float* __restrict__ x,
        const float* __restrict__ W, float* __restrict__ y) {
    __shared__ unsigned short sWT[64 * WT_STR];   // 17.4 KB, bf16 WT[c][k]
    const int tid = threadIdx.x;
    for (int i = tid; i < IN_CH * OUT_CH; i += 256) {   // stage + convert W once
        int k = i >> 6, c = i & 63;
        unsigned int u = __float_as_uint(W[i]);
        u = (u + 0x7fffu + ((u >> 16) & 1u)) >> 16;     // RNE to bf16
        sWT[c * WT_STR + k] = (unsigned short)u;
    }
    __syncthreads();
    const int lane = tid & 63;
    const int quad = lane >> 4;
    const int c15  = lane & 15;

    short8 bf[4][4];                      // [k-chunk][n-tile], resident
    #pragma unroll
    for (int t = 0; t < 4; ++t)
        #pragma unroll
        for (int ch = 0; ch < 4; ++ch)
            bf[ch][t] = *(const short8*)&sWT[(t * 16 + c15) * WT_STR + ch * 32 + quad * 8];

    const int wave = (blockIdx.x * 256 + tid) >> 6;     // 0..1023
    for (int tile = wave; tile < N_NODES / 16; tile += 1024) {
        const float* xr = x + ((size_t)tile * 16 + c15) * IN_CH;
        float4v acc[4] = {{0.f,0.f,0.f,0.f},{0.f,0.f,0.f,0.f},
                          {0.f,0.f,0.f,0.f},{0.f,0.f,0.f,0.f}};
        #pragma unroll
        for (int ch = 0; ch < 4; ++ch) {
            float4 f0 = *(const float4*)(xr + ch * 32 + quad * 8);
            float4 f1 = *(const float4*)(xr + ch * 32 + quad * 8 + 4);
            unsigned int d0 = bpack(f0.x, f0.y), d1 = bpack(f0.z, f0.w);
            unsigned int d2 = bpack(f1.x, f1.y), d3 = bpack(f1.z, f1.w);
            short8 a;
            a[0] = (short)d0; a[1] = (short)(d0 >> 16);
            a[2] = (short)d1; a[3] = (short)(d1 >> 16);
            a[4] = (short)d2; a[5] = (short)(d2 >> 16);
            a[6] = (short)d3; a[7] = (short)(d3 >> 16);
            #pragma unroll
            for (int t = 0; t < 4; ++t)
                acc[t] = __builtin_amdgcn_mfma_f32_16x16x32_bf16(a, bf[ch][t], acc[t], 0, 0, 0);
        }
        #pragma unroll
        for (int t = 0; t < 4; ++t)
            #pragma unroll
            for (int r = 0; r < 4; ++r)
                y[((size_t)tile * 16 + quad * 4 + r) * OUT_CH + t * 16 + c15] = acc[t][r];
    }
}

// =================== K4: z0 = D^-1/2 y (fp32 -> bf16) ===================
__global__ __launch_bounds__(256) void scale_z0(const float* __restrict__ y,
        const unsigned char* __restrict__ fill8, uint4* __restrict__ z0) {
    int gid = blockIdx.x * 256 + threadIdx.x;
    if (gid >= N_NODES * 8) return;
    int n = gid >> 3, q = gid & 7;
    float d = rsqrtf((float)((int)fill8[n] + 1));
    float4 a = ((const float4*)y)[n * 16 + q * 2];
    float4 b = ((const float4*)y)[n * 16 + q * 2 + 1];
    uint4 pk;
    pk.x = bpack(d * a.x, d * a.y);
    pk.y = bpack(d * a.z, d * a.w);
    pk.z = bpack(d * b.x, d * b.y);
    pk.w = bpack(d * b.z, d * b.w);
    z0[gid] = pk;
}

// =================== K5/K6: unweighted (A+I) gather + diagonal epilogue ===================
// Wave per target; 8 groups x 8 lanes; lane q = channels q*8..+7 (uint4 of 8
// bf16, one 128B row per group). Single consolidated list (R12 form).
__global__ __launch_bounds__(256) void hop_gather(const uint4* __restrict__ hin,
        void* __restrict__ hout, const unsigned char* __restrict__ fill8,
        const unsigned short* __restrict__ esrc, const float* __restrict__ bias,
        int last) {
    int lane = threadIdx.x & 63;
    int g = lane >> 3;
    int q = lane & 7;
    int t = __builtin_amdgcn_readfirstlane(blockIdx.x * 4 + (threadIdx.x >> 6));
    if (t >= N_NODES) return;
    int deg = fill8[t];

    float acc[8] = {};
    if (g == 0) {                      // self-loop (weight 1)
        uint4 r = hin[t * 8 + q];
        const unsigned int rw[4] = { r.x, r.y, r.z, r.w };
        #pragma unroll
        for (int j = 0; j < 4; ++j) {
            acc[2 * j]     = __uint_as_float(rw[j] << 16);
            acc[2 * j + 1] = __uint_as_float(rw[j] & 0xffff0000u);
        }
    }
    for (int base = 0; base < deg; base += 8) {
        int e = base + g;
        if (e < deg) {
            int s = (int)esrc[(size_t)e * N_NODES + t];
            uint4 r = hin[s * 8 + q];
            const unsigned int rw[4] = { r.x, r.y, r.z, r.w };
            #pragma unroll
            for (int j = 0; j < 4; ++j) {
                acc[2 * j]     += __uint_as_float(rw[j] << 16);
                acc[2 * j + 1] += __uint_as_float(rw[j] & 0xffff0000u);
            }
        }
    }
    #pragma unroll
    for (int j = 0; j < 8; ++j) {
        acc[j] += __shfl_xor(acc[j], 8);
        acc[j] += __shfl_xor(acc[j], 16);
        acc[j] += __shfl_xor(acc[j], 32);
    }
    if (g == 0) {
        if (!last) {                   // z1 = u1 / (deg+1), bf16
            float rdeg = 1.0f / (float)(deg + 1);
            uint4 pk;
            pk.x = bpack(acc[0] * rdeg, acc[1] * rdeg);
            pk.y = bpack(acc[2] * rdeg, acc[3] * rdeg);
            pk.z = bpack(acc[4] * rdeg, acc[5] * rdeg);
            pk.w = bpack(acc[6] * rdeg, acc[7] * rdeg);
            ((uint4*)hout)[t * 8 + q] = pk;
        } else {                       // out = dinv*u2 + b, fp32
            float d = rsqrtf((float)(deg + 1));
            float4 b0 = ((const float4*)bias)[q * 2];
            float4 b1 = ((const float4*)bias)[q * 2 + 1];
            float4 o0 = make_float4(d * acc[0] + b0.x, d * acc[1] + b0.y,
                                    d * acc[2] + b0.z, d * acc[3] + b0.w);
            float4 o1 = make_float4(d * acc[4] + b1.x, d * acc[5] + b1.y,
                                    d * acc[6] + b1.z, d * acc[7] + b1.w);
            ((float4*)hout)[t * 16 + q * 2]     = o0;
            ((float4*)hout)[t * 16 + q * 2 + 1] = o1;
        }
    }
}

// =================== launch ===================
extern "C" void kernel_launch(void* const* d_in, const int* in_sizes, int n_in,
                              void* d_out, int out_size, void* d_ws, size_t ws_size,
                              hipStream_t stream) {
    const float* x  = (const float*)d_in[0];
    const int*   ei = (const int*)d_in[1];
    const float* W  = (const float*)d_in[2];
    const float* b  = (const float*)d_in[3];
    float*       out = (float*)d_out;

    const int* row = ei;
    const int* col = ei + N_EDGES;

    // ws (~30 MB): gcur | binbuf | esrc | fill8 | y | z0 | z1
    char* ws = (char*)d_ws;
    size_t a = 0;
    auto alloc = [&](size_t bytes) { char* p = ws + a; a = (a + bytes + 255) & ~(size_t)255; return p; };
    int*            gcur   = (int*)           alloc(NBINS * sizeof(int));
    unsigned int*   binbuf = (unsigned int*)  alloc((size_t)NBINS * BINCAP * 4);
    unsigned short* esrc   = (unsigned short*)alloc((size_t)PCAP * N_NODES * 2);
    unsigned char*  fill8  = (unsigned char*) alloc(N_NODES);
    float*          y      = (float*)         alloc((size_t)N_NODES * OUT_CH * 4);
    unsigned int*   z0     = (unsigned int*)  alloc((size_t)N_NODES * OUT_CH * 2);
    unsigned int*   z1     = (unsigned int*)  alloc((size_t)N_NODES * OUT_CH * 2);

    hipMemsetAsync(gcur, 0, NBINS * sizeof(int), stream);

    const int B = 256;
    int gS = (N_NODES * 8 + B - 1) / B;   // 1563
    int gH = (N_NODES + 3) / 4;           // 12500

    scatter_a<<<256, B, 0, stream>>>(row, col, binbuf, gcur);
    scatter_b<<<NBINS, 1024, 0, stream>>>(binbuf, gcur, esrc, fill8);
    gemm_mfma<<<256, B, 0, stream>>>(x, W, y);
    scale_z0 <<<gS, B, 0, stream>>>(y, fill8, (uint4*)z0);
    hop_gather<<<gH, B, 0, stream>>>((const uint4*)z0, (void*)z1, fill8, esrc, b, 0);
    hop_gather<<<gH, B, 0, stream>>>((const uint4*)z1, (void*)out, fill8, esrc, b, 1);
}

// Round 15
// 165.803 us; speedup vs baseline: 1.5616x; 1.1070x over previous
//
#include <hip/hip_runtime.h>

#define N_NODES 50000
#define IN_CH   128
#define OUT_CH  64
#define N_EDGES 800000
#define NBINS   49      // bin = t >> 10
#define LBCAP   128     // per-(block,bin) LDS cap; Poisson(32.7), P(>128)~0
#define BINCAP  20000   // per-bin global cap; mean 16.3K, sd 128
#define PCAP    64      // esrc planes; deg Poisson(16), P(>64)~1e-18
#define WT_STR  136     // bf16 per WT row
#define SA_B    500     // scatter_a blocks (2/CU); 500*1600 = 800000 exactly
#define SA_E    1600
#define SB_B    49      // scatter_b blocks (single-writer per bin)
#define GEMM_BL 196     // gemm blocks in fused K2; 196*16 waves >= 3125 tiles

// NOTE (R9): ~92us of dur_us is harness 256MB ws poison fills. Budget = dur-92.
// NOTE (R1): integer inputs arrive as int32.
// NOTE (R12-R14): random fine-grain global stores -> ~50MB partial-line traffic;
// two-phase binning fixes writes (R13: 4.2MB) BUT the phases must (a) run at
// >=2 blocks/CU, (b) not serialize bin copies, (c) overlap the gemm in the same
// dispatch (R10-R12 got the gemm for free under the scatter; R14 paid serially).

using short8  = __attribute__((ext_vector_type(8))) short;
using float4v = __attribute__((ext_vector_type(4))) float;

__device__ __forceinline__ unsigned int bpack(float a, float b) {
    unsigned int ua = __float_as_uint(a), ub = __float_as_uint(b);
    unsigned int ra = (ua + 0x7fffu + ((ua >> 16) & 1u)) >> 16;
    unsigned int rb = (ub + 0x7fffu + ((ub >> 16) & 1u)) & 0xffff0000u;
    return (ra & 0xffffu) | rb;
}

// =================== K1: scatter phase A — bin edges, dense append ===================
// 500 blocks x 1600 edges, read-once coalesced int4. Bin-append in LDS, one
// global atomic per (block,bin), then WAVE-PARALLEL dense copy (wave w owns
// bins w, w+4, ...) -- no serial 49-round tail.
__global__ __launch_bounds__(256) void scatter_a(const int* __restrict__ row,
        const int* __restrict__ col, unsigned int* __restrict__ binbuf,
        int* __restrict__ gcur) {
    __shared__ unsigned int sbuf[NBINS][LBCAP];   // 25 KB
    __shared__ int scnt[NBINS];
    __shared__ int sdst[NBINS];
    const int tid = threadIdx.x;
    if (tid < NBINS) scnt[tid] = 0;
    __syncthreads();
    const int e0 = blockIdx.x * SA_E;
    for (int i = tid; i < SA_E / 4; i += 256) {      // 400 int4 per block
        int e = e0 + i * 4;
        int4 t4 = *(const int4*)&col[e];
        int4 s4 = *(const int4*)&row[e];
        const int ts[4] = { t4.x, t4.y, t4.z, t4.w };
        const int ss[4] = { s4.x, s4.y, s4.z, s4.w };
        #pragma unroll
        for (int j = 0; j < 4; ++j) {
            int b = ts[j] >> 10;
            int pos = atomicAdd(&scnt[b], 1);        // LDS atomic
            if (pos < LBCAP)
                sbuf[b][pos] = ((unsigned)(ts[j] & 1023) << 16) | (unsigned)ss[j];
        }
    }
    __syncthreads();
    if (tid < NBINS) {
        int c = scnt[tid]; if (c > LBCAP) c = LBCAP; scnt[tid] = c;
        sdst[tid] = atomicAdd(&gcur[tid], c);        // 1 global atomic/bin
    }
    __syncthreads();
    const int wave = tid >> 6, lane = tid & 63;
    for (int b = wave; b < NBINS; b += 4) {          // wave-parallel dense copy
        int c = scnt[b];
        size_t d = (size_t)b * BINCAP + sdst[b];
        for (int i = lane; i < c; i += 64)
            binbuf[d + i] = sbuf[b][i];
    }
}

// =================== K2 (fused): scatter_b (blocks [0,49)) || MFMA gemm ===================
// scatter_b: per-bin CSR build, single-writer 2KB stripes -> dense writebacks.
// gemm: wave = one 16-node tile x 64 ch, K=128 bf16 MFMA; A packed in-reg from
// global fp32; B-frags from LDS once, resident in VGPRs. 245 blocks total.
__global__ __launch_bounds__(1024) void scatb_gemm(
        const unsigned int* __restrict__ binbuf, const int* __restrict__ gcur,
        unsigned short* __restrict__ esrc, unsigned char* __restrict__ fill8,
        const float* __restrict__ x, const float* __restrict__ W,
        float* __restrict__ y) {
    const int bid = blockIdx.x, tid = threadIdx.x;
    if (bid < SB_B) {   // ---- scatter_b ----
        __shared__ int lcnt[1024];
        const int t0 = bid << 10;
        lcnt[tid] = 0;
        __syncthreads();
        int cnt = gcur[bid]; if (cnt > BINCAP) cnt = BINCAP;
        const unsigned int* src = binbuf + (size_t)bid * BINCAP;
        for (int i = tid; i < cnt; i += 1024) {
            unsigned int e = src[i];                 // dense read
            int tl = e >> 16;
            int pos = atomicAdd(&lcnt[tl], 1);       // LDS atomic
            int t = t0 + tl;
            if (pos < PCAP && t < N_NODES)
                esrc[(size_t)pos * N_NODES + t] = (unsigned short)(e & 0xffffu);
        }
        __syncthreads();
        int t = t0 + tid;
        if (t < N_NODES) {
            int v = lcnt[tid]; if (v > PCAP) v = PCAP;
            fill8[t] = (unsigned char)v;
        }
        return;
    }
    // ---- gemm ----
    __shared__ unsigned short sWT[64 * WT_STR];      // 17.4 KB, bf16 WT[c][k]
    for (int i = tid; i < IN_CH * OUT_CH; i += 1024) {
        int k = i >> 6, c = i & 63;
        unsigned int u = __float_as_uint(W[i]);
        u = (u + 0x7fffu + ((u >> 16) & 1u)) >> 16;  // RNE to bf16
        sWT[c * WT_STR + k] = (unsigned short)u;
    }
    __syncthreads();
    const int lane = tid & 63;
    const int quad = lane >> 4;
    const int c15  = lane & 15;
    const int tile = (bid - SB_B) * 16 + (tid >> 6); // one tile per wave
    if (tile >= N_NODES / 16) return;                // after the only barrier

    short8 bf[4][4];
    #pragma unroll
    for (int t = 0; t < 4; ++t)
        #pragma unroll
        for (int ch = 0; ch < 4; ++ch)
            bf[ch][t] = *(const short8*)&sWT[(t * 16 + c15) * WT_STR + ch * 32 + quad * 8];

    const float* xr = x + ((size_t)tile * 16 + c15) * IN_CH;
    float4v acc[4] = {{0.f,0.f,0.f,0.f},{0.f,0.f,0.f,0.f},
                      {0.f,0.f,0.f,0.f},{0.f,0.f,0.f,0.f}};
    #pragma unroll
    for (int ch = 0; ch < 4; ++ch) {
        float4 f0 = *(const float4*)(xr + ch * 32 + quad * 8);
        float4 f1 = *(const float4*)(xr + ch * 32 + quad * 8 + 4);
        unsigned int d0 = bpack(f0.x, f0.y), d1 = bpack(f0.z, f0.w);
        unsigned int d2 = bpack(f1.x, f1.y), d3 = bpack(f1.z, f1.w);
        short8 a8;
        a8[0] = (short)d0; a8[1] = (short)(d0 >> 16);
        a8[2] = (short)d1; a8[3] = (short)(d1 >> 16);
        a8[4] = (short)d2; a8[5] = (short)(d2 >> 16);
        a8[6] = (short)d3; a8[7] = (short)(d3 >> 16);
        #pragma unroll
        for (int t = 0; t < 4; ++t)
            acc[t] = __builtin_amdgcn_mfma_f32_16x16x32_bf16(a8, bf[ch][t], acc[t], 0, 0, 0);
    }
    #pragma unroll
    for (int t = 0; t < 4; ++t)
        #pragma unroll
        for (int r = 0; r < 4; ++r)
            y[((size_t)tile * 16 + quad * 4 + r) * OUT_CH + t * 16 + c15] = acc[t][r];
}

// =================== K3: z0 = D^-1/2 y (fp32 -> bf16) ===================
__global__ __launch_bounds__(256) void scale_z0(const float* __restrict__ y,
        const unsigned char* __restrict__ fill8, uint4* __restrict__ z0) {
    int gid = blockIdx.x * 256 + threadIdx.x;
    if (gid >= N_NODES * 8) return;
    int n = gid >> 3, q = gid & 7;
    float d = rsqrtf((float)((int)fill8[n] + 1));
    float4 a = ((const float4*)y)[n * 16 + q * 2];
    float4 b = ((const float4*)y)[n * 16 + q * 2 + 1];
    uint4 pk;
    pk.x = bpack(d * a.x, d * a.y);
    pk.y = bpack(d * a.z, d * a.w);
    pk.z = bpack(d * b.x, d * b.y);
    pk.w = bpack(d * b.z, d * b.w);
    z0[gid] = pk;
}

// =================== K4/K5: unweighted (A+I) gather + diagonal epilogue ===================
__global__ __launch_bounds__(256) void hop_gather(const uint4* __restrict__ hin,
        void* __restrict__ hout, const unsigned char* __restrict__ fill8,
        const unsigned short* __restrict__ esrc, const float* __restrict__ bias,
        int last) {
    int lane = threadIdx.x & 63;
    int g = lane >> 3;
    int q = lane & 7;
    int t = __builtin_amdgcn_readfirstlane(blockIdx.x * 4 + (threadIdx.x >> 6));
    if (t >= N_NODES) return;
    int deg = fill8[t];

    float acc[8] = {};
    if (g == 0) {                      // self-loop (weight 1)
        uint4 r = hin[t * 8 + q];
        const unsigned int rw[4] = { r.x, r.y, r.z, r.w };
        #pragma unroll
        for (int j = 0; j < 4; ++j) {
            acc[2 * j]     = __uint_as_float(rw[j] << 16);
            acc[2 * j + 1] = __uint_as_float(rw[j] & 0xffff0000u);
        }
    }
    for (int base = 0; base < deg; base += 8) {
        int e = base + g;
        if (e < deg) {
            int s = (int)esrc[(size_t)e * N_NODES + t];
            uint4 r = hin[s * 8 + q];
            const unsigned int rw[4] = { r.x, r.y, r.z, r.w };
            #pragma unroll
            for (int j = 0; j < 4; ++j) {
                acc[2 * j]     += __uint_as_float(rw[j] << 16);
                acc[2 * j + 1] += __uint_as_float(rw[j] & 0xffff0000u);
            }
        }
    }
    #pragma unroll
    for (int j = 0; j < 8; ++j) {
        acc[j] += __shfl_xor(acc[j], 8);
        acc[j] += __shfl_xor(acc[j], 16);
        acc[j] += __shfl_xor(acc[j], 32);
    }
    if (g == 0) {
        if (!last) {                   // z1 = u1 / (deg+1), bf16
            float rdeg = 1.0f / (float)(deg + 1);
            uint4 pk;
            pk.x = bpack(acc[0] * rdeg, acc[1] * rdeg);
            pk.y = bpack(acc[2] * rdeg, acc[3] * rdeg);
            pk.z = bpack(acc[4] * rdeg, acc[5] * rdeg);
            pk.w = bpack(acc[6] * rdeg, acc[7] * rdeg);
            ((uint4*)hout)[t * 8 + q] = pk;
        } else {                       // out = dinv*u2 + b, fp32
            float d = rsqrtf((float)(deg + 1));
            float4 b0 = ((const float4*)bias)[q * 2];
            float4 b1 = ((const float4*)bias)[q * 2 + 1];
            float4 o0 = make_float4(d * acc[0] + b0.x, d * acc[1] + b0.y,
                                    d * acc[2] + b0.z, d * acc[3] + b0.w);
            float4 o1 = make_float4(d * acc[4] + b1.x, d * acc[5] + b1.y,
                                    d * acc[6] + b1.z, d * acc[7] + b1.w);
            ((float4*)hout)[t * 16 + q * 2]     = o0;
            ((float4*)hout)[t * 16 + q * 2 + 1] = o1;
        }
    }
}

// =================== launch ===================
extern "C" void kernel_launch(void* const* d_in, const int* in_sizes, int n_in,
                              void* d_out, int out_size, void* d_ws, size_t ws_size,
                              hipStream_t stream) {
    const float* x  = (const float*)d_in[0];
    const int*   ei = (const int*)d_in[1];
    const float* W  = (const float*)d_in[2];
    const float* b  = (const float*)d_in[3];
    float*       out = (float*)d_out;

    const int* row = ei;
    const int* col = ei + N_EDGES;

    // ws (~30 MB): gcur | binbuf | esrc | fill8 | y | z0 | z1
    char* ws = (char*)d_ws;
    size_t a = 0;
    auto alloc = [&](size_t bytes) { char* p = ws + a; a = (a + bytes + 255) & ~(size_t)255; return p; };
    int*            gcur   = (int*)           alloc(NBINS * sizeof(int));
    unsigned int*   binbuf = (unsigned int*)  alloc((size_t)NBINS * BINCAP * 4);
    unsigned short* esrc   = (unsigned short*)alloc((size_t)PCAP * N_NODES * 2);
    unsigned char*  fill8  = (unsigned char*) alloc(N_NODES);
    float*          y      = (float*)         alloc((size_t)N_NODES * OUT_CH * 4);
    unsigned int*   z0     = (unsigned int*)  alloc((size_t)N_NODES * OUT_CH * 2);
    unsigned int*   z1     = (unsigned int*)  alloc((size_t)N_NODES * OUT_CH * 2);

    hipMemsetAsync(gcur, 0, NBINS * sizeof(int), stream);

    const int B = 256;
    int gS = (N_NODES * 8 + B - 1) / B;   // 1563
    int gH = (N_NODES + 3) / 4;           // 12500

    scatter_a<<<SA_B, B, 0, stream>>>(row, col, binbuf, gcur);
    scatb_gemm<<<SB_B + GEMM_BL, 1024, 0, stream>>>(binbuf, gcur, esrc, fill8, x, W, y);
    scale_z0 <<<gS, B, 0, stream>>>(y, fill8, (uint4*)z0);
    hop_gather<<<gH, B, 0, stream>>>((const uint4*)z0, (void*)z1, fill8, esrc, b, 0);
    hop_gather<<<gH, B, 0, stream>>>((const uint4*)z1, (void*)out, fill8, esrc, b, 1);
}